// Round 1
// baseline (52.013 us; speedup 1.0000x reference)
//
#include <hip/hip_runtime.h>

// Problem dims (fixed by reference setup_inputs):
#define BATCH 1024
#define NSEQ  512
#define NF    64
#define TBL_N (NSEQ + 1)   // counts range 0..512
#define HIST_BINS 1024     // ids in [0,1000)

// ---------------------------------------------------------------------------
// Kernel 1: build lookup table  tbl[c][g] = b2[g] + sum_f relu(c*W1[f]+b1[f]) * W2[f][g]
// Grid: TBL_N blocks x NF threads. Tiny (513*64*64 MACs).
// ---------------------------------------------------------------------------
__global__ void build_table_kernel(const float* __restrict__ W1,
                                   const float* __restrict__ b1,
                                   const float* __restrict__ W2,
                                   const float* __restrict__ b2,
                                   float* __restrict__ tbl) {
    const int c = blockIdx.x;     // count value 0..512
    const int g = threadIdx.x;    // output feature 0..63
    const float cf = (float)c;
    float acc = b2[g];
#pragma unroll 8
    for (int f = 0; f < NF; ++f) {
        float h = fmaxf(cf * W1[f] + b1[f], 0.0f);
        acc += h * W2[f * NF + g];
    }
    tbl[c * NF + g] = acc;
}

// ---------------------------------------------------------------------------
// Kernel 2: per batch row -- histogram ids, look up counts, gather table rows.
// One block per batch row, 256 threads.
// ---------------------------------------------------------------------------
__global__ __launch_bounds__(256) void cooc_encode_kernel(
        const int* __restrict__ src_ids,
        const int* __restrict__ dst_ids,
        const float* __restrict__ tbl,
        float* __restrict__ out_src,
        float* __restrict__ out_dst) {
    __shared__ int s_src[NSEQ];
    __shared__ int s_dst[NSEQ];
    __shared__ int hist_s[HIST_BINS];
    __shared__ int hist_d[HIST_BINS];
    __shared__ int c_ss[NSEQ], c_sd[NSEQ], c_dd[NSEQ], c_ds[NSEQ];

    const int b = blockIdx.x;
    const int t = threadIdx.x;

    // zero histograms
#pragma unroll
    for (int i = t; i < HIST_BINS; i += 256) { hist_s[i] = 0; hist_d[i] = 0; }
    // stage id rows
#pragma unroll
    for (int i = t; i < NSEQ; i += 256) {
        s_src[i] = src_ids[(size_t)b * NSEQ + i];
        s_dst[i] = dst_ids[(size_t)b * NSEQ + i];
    }
    __syncthreads();

    // build histograms (guard padded id = -1)
#pragma unroll
    for (int i = t; i < NSEQ; i += 256) {
        int si = s_src[i], di = s_dst[i];
        if (si >= 0) atomicAdd(&hist_s[si], 1);
        if (di >= 0) atomicAdd(&hist_d[di], 1);
    }
    __syncthreads();

    // per-position counts (padded -> 0, matching reference freq zeroing)
#pragma unroll
    for (int i = t; i < NSEQ; i += 256) {
        int si = s_src[i], di = s_dst[i];
        c_ss[i] = (si >= 0) ? hist_s[si] : 0;
        c_sd[i] = (si >= 0) ? hist_d[si] : 0;
        c_dd[i] = (di >= 0) ? hist_d[di] : 0;
        c_ds[i] = (di >= 0) ? hist_s[di] : 0;
    }
    __syncthreads();

    // write phase: out[b,n,:] = tbl[c1] + tbl[c2], vectorized as float4
    const float4* __restrict__ tbl4 = (const float4*)tbl;
    float4* __restrict__ o0 = (float4*)(out_src + (size_t)b * NSEQ * NF);
    float4* __restrict__ o1 = (float4*)(out_dst + (size_t)b * NSEQ * NF);
    const int NV = NSEQ * NF / 4;   // 8192 float4 per output per row-block
#pragma unroll 4
    for (int e = t; e < NV; e += 256) {
        int n  = e >> 4;            // NF/4 = 16 float4 per position
        int f4 = e & 15;
        float4 a0 = tbl4[c_ss[n] * (NF / 4) + f4];
        float4 a1 = tbl4[c_sd[n] * (NF / 4) + f4];
        o0[e] = make_float4(a0.x + a1.x, a0.y + a1.y, a0.z + a1.z, a0.w + a1.w);
        float4 d0 = tbl4[c_dd[n] * (NF / 4) + f4];
        float4 d1 = tbl4[c_ds[n] * (NF / 4) + f4];
        o1[e] = make_float4(d0.x + d1.x, d0.y + d1.y, d0.z + d1.z, d0.w + d1.w);
    }
}

extern "C" void kernel_launch(void* const* d_in, const int* in_sizes, int n_in,
                              void* d_out, int out_size, void* d_ws, size_t ws_size,
                              hipStream_t stream) {
    const int*   src_ids = (const int*)d_in[0];
    const int*   dst_ids = (const int*)d_in[1];
    const float* W1 = (const float*)d_in[2];   // [1, F]
    const float* b1 = (const float*)d_in[3];   // [F]
    const float* W2 = (const float*)d_in[4];   // [F, F]
    const float* b2 = (const float*)d_in[5];   // [F]

    float* out_src = (float*)d_out;                               // [B, N, F]
    float* out_dst = (float*)d_out + (size_t)BATCH * NSEQ * NF;   // [B, N, F]

    float* tbl = (float*)d_ws;   // TBL_N * NF floats = 131,328 B

    build_table_kernel<<<TBL_N, NF, 0, stream>>>(W1, b1, W2, b2, tbl);
    cooc_encode_kernel<<<BATCH, 256, 0, stream>>>(src_ids, dst_ids, tbl,
                                                  out_src, out_dst);
}